// Round 2
// baseline (199.963 us; speedup 1.0000x reference)
//
#include <hip/hip_runtime.h>
#include <math.h>

// ---------------- workspace layout (float offsets) ----------------
#define OFF_W2P 0              // [64][224]  Wm2 pre-contracted with P (c-major rows of 224)
#define OFF_B2P 14336          // [224]      bm2 pre-contracted
#define WS_FLOATS 14560

#define SC_Y0 0.0180421959121758f   // (1/sqrt(32))*(1/sqrt(96))
#define SC_Y2 0.015625f             // (1/sqrt(32))*(1/sqrt(128)) = 1/64
#define S2f 0.70710678118654752f
#define S6f 0.40824829046386302f
#define TWOS2f 1.41421356237309505f
#define TWOS6f 0.81649658092772603f
#define ISQRT3 0.57735026918962576f
#define ISQRT5 0.44721359549995794f
#define H0SC 0.08838834764831845f   // 1/sqrt(128)
#define H1SC 0.125f                 // 1/sqrt(64)
#define H2SC 0.17677669529663689f   // 1/sqrt(32)

__device__ __constant__ int KARR[7] = {0, 1, 2, 4, 5, 6, 8};

// ---------------- prep: Wm2p, bm2p, zero out ----------------
__global__ __launch_bounds__(256) void prep_kernel(
    const float* __restrict__ Wm2, const float* __restrict__ bm2,
    const float* __restrict__ P0, const float* __restrict__ P2,
    float* __restrict__ ws, float* __restrict__ out) {
  int j = blockIdx.x * 256 + threadIdx.x;
  if (j < 2304) out[j] = 0.f;

  if (j < 14336) {
    int s = j >> 11; int rem = j & 2047; int c = rem >> 5; int u = rem & 31;
    int k = KARR[s];
    const float* P;
    float sc;
    switch (s) {
      case 0: P = P0;      sc = SC_Y0; break;
      case 1: P = P2;      sc = SC_Y2; break;
      case 2: P = P0 + 32; sc = SC_Y0; break;
      case 3: P = P2 + 32; sc = SC_Y2; break;
      case 4: P = P2 + 64; sc = SC_Y2; break;
      case 5: P = P0 + 64; sc = SC_Y0; break;
      default: P = P2 + 96; sc = SC_Y2; break;
    }
    const float4* w4 = (const float4*)(Wm2 + c * 9216 + k * 1024 + u * 32);
    const float4* p4 = (const float4*)P;
    float acc = 0.f;
#pragma unroll
    for (int q = 0; q < 8; ++q) {
      float4 a = w4[q], b = p4[q];
      acc += a.x * b.x + a.y * b.y + a.z * b.z + a.w * b.w;
    }
    ws[OFF_W2P + c * 224 + s * 32 + u] = acc * sc;
  } else if (j < 14560) {
    int i = j - 14336; int s = i >> 5; int u = i & 31; int k = KARR[s];
    const float* P;
    float sc;
    switch (s) {
      case 0: P = P0;      sc = SC_Y0; break;
      case 1: P = P2;      sc = SC_Y2; break;
      case 2: P = P0 + 32; sc = SC_Y0; break;
      case 3: P = P2 + 32; sc = SC_Y2; break;
      case 4: P = P2 + 64; sc = SC_Y2; break;
      case 5: P = P0 + 64; sc = SC_Y0; break;
      default: P = P2 + 96; sc = SC_Y2; break;
    }
    const float* b = bm2 + k * 1024 + u * 32;
    float acc = 0.f;
#pragma unroll
    for (int w = 0; w < 32; ++w) acc += b[w] * P[w];
    ws[OFF_B2P + s * 32 + u] = acc * sc;
  }
}

// ---------------- fused: hidden GEMM -> V GEMM (LDS) -> h + path math -> atomics ----------------
// LDS overlay: [0,28672): xs[32][132] (phase 0-1a) then V[32][224] (phase 1b+)
//              [28672,37888): hiT[64][36]
//              [37888,38912): sphs[32][8]
//              [38912,39040): batch_s[32]
__global__ __launch_bounds__(256) void fused_kernel(
    const float* __restrict__ xs_g, const float* __restrict__ xsph,
    const int* __restrict__ batch,
    const float* __restrict__ W0e, const float* __restrict__ W1o,
    const float* __restrict__ W2e,
    const float* __restrict__ Wm1, const float* __restrict__ bm1,
    const float* __restrict__ ws, float* __restrict__ out, const float norm2) {
  __shared__ __align__(16) char smem[39040];
  float (*xs)[132] = (float (*)[132])smem;
  float (*V)[224]  = (float (*)[224])smem;
  float (*hiT)[36] = (float (*)[36])(smem + 28672);
  float (*sphs)[8] = (float (*)[8])(smem + 37888);
  int* batch_s     = (int*)(smem + 38912);

  const int tid = threadIdx.x;
  const int n0 = blockIdx.x * 32;   // 625 * 32 == 20000 exactly

  // ---- phase 0: stage x_scalar tile, batch ----
  for (int idx = tid; idx < 1024; idx += 256) {
    const int row = idx >> 5, c4 = idx & 31;
    *(float4*)&xs[row][c4 * 4] = *(const float4*)(xs_g + (n0 + row) * 128 + c4 * 4);
  }
  if (tid < 32) batch_s[tid] = batch[n0 + tid];
  __syncthreads();

  // ---- phase 1a: hidden[n][c] = silu(x@Wm1 + bm1), stored transposed hiT[c][n] ----
  {
    const int cg = tid & 15, ng = tid >> 4;
    const int c0 = cg * 4, nl = ng * 2;
    float acc[2][4] = {{0.f}};
#pragma unroll 4
    for (int mq = 0; mq < 32; ++mq) {
      float4 xv[2];
      xv[0] = *(float4*)&xs[nl][mq * 4];
      xv[1] = *(float4*)&xs[nl + 1][mq * 4];
      float4 wv[4];
#pragma unroll
      for (int r = 0; r < 4; ++r) wv[r] = *(const float4*)(Wm1 + (mq * 4 + r) * 64 + c0);
#pragma unroll
      for (int r = 0; r < 4; ++r) {
        const float4 w = wv[r];
#pragma unroll
        for (int i = 0; i < 2; ++i) {
          const float xr = (r == 0) ? xv[i].x : (r == 1) ? xv[i].y : (r == 2) ? xv[i].z : xv[i].w;
          acc[i][0] += xr * w.x; acc[i][1] += xr * w.y;
          acc[i][2] += xr * w.z; acc[i][3] += xr * w.w;
        }
      }
    }
    const float4 bb = *(const float4*)(bm1 + c0);
#pragma unroll
    for (int jj = 0; jj < 4; ++jj) {
      float zz[2];
#pragma unroll
      for (int i = 0; i < 2; ++i) {
        float z = acc[i][jj] + ((jj == 0) ? bb.x : (jj == 1) ? bb.y : (jj == 2) ? bb.z : bb.w);
        zz[i] = z / (1.f + __expf(-z));
      }
      *(float2*)&hiT[c0 + jj][nl] = make_float2(zz[0], zz[1]);
    }
  }
  __syncthreads();

  // ---- phase 1b: V[n][o] = hidden@W2p + b2p  (V overlays dead xs region) ----
  if (tid < 224) {
    const int og = tid >> 3, ng = tid & 7;
    const int o0 = og * 8, nl = ng * 4;
    const float4 blo = *(const float4*)(ws + OFF_B2P + o0);
    const float4 bhi = *(const float4*)(ws + OFF_B2P + o0 + 4);
    float acc[4][8];
#pragma unroll
    for (int i = 0; i < 4; ++i) {
      acc[i][0] = blo.x; acc[i][1] = blo.y; acc[i][2] = blo.z; acc[i][3] = blo.w;
      acc[i][4] = bhi.x; acc[i][5] = bhi.y; acc[i][6] = bhi.z; acc[i][7] = bhi.w;
    }
#pragma unroll 2
    for (int c = 0; c < 64; ++c) {
      const float4 hv = *(float4*)&hiT[c][nl];
      const float4 wlo = *(const float4*)(ws + OFF_W2P + c * 224 + o0);
      const float4 whi = *(const float4*)(ws + OFF_W2P + c * 224 + o0 + 4);
      const float hvv[4] = {hv.x, hv.y, hv.z, hv.w};
      const float wv[8] = {wlo.x, wlo.y, wlo.z, wlo.w, whi.x, whi.y, whi.z, whi.w};
#pragma unroll
      for (int i = 0; i < 4; ++i)
#pragma unroll
        for (int jj = 0; jj < 8; ++jj) acc[i][jj] += hvv[i] * wv[jj];
    }
#pragma unroll
    for (int i = 0; i < 4; ++i) {
      float4 a = {acc[i][0], acc[i][1], acc[i][2], acc[i][3]};
      float4 b = {acc[i][4], acc[i][5], acc[i][6], acc[i][7]};
      *(float4*)&V[nl + i][o0] = a;
      *(float4*)&V[nl + i][o0 + 4] = b;
    }
  }
  __syncthreads();

  // ---- phase 2+3: per-(n,u) h-projections + path math + width-32 reduce ----
  const int lane = tid & 63, wid = tid >> 6;
  const int half = lane >> 5, u = lane & 31;
  const float* W0u = W0e + u;
  const float* W1u = W1o + u;
  const float* W2u = W2e + u;

  for (int p = 0; p < 4; ++p) {
    const int nloc = p * 8 + wid * 2 + half;
    const float4* x4 = (const float4*)(xsph + (size_t)(n0 + nloc) * 480);

    float h0 = 0.f;
#pragma unroll 8
    for (int mq = 0; mq < 32; ++mq) {
      const float4 xv = x4[mq];
      h0 += xv.x * W0u[(mq * 4 + 0) * 32] + xv.y * W0u[(mq * 4 + 1) * 32] +
            xv.z * W0u[(mq * 4 + 2) * 32] + xv.w * W0u[(mq * 4 + 3) * 32];
    }
    h0 *= H0SC;

    float h1v[3] = {0.f, 0.f, 0.f};
#pragma unroll 4
    for (int mq = 0; mq < 16; ++mq) {
      const float4 a0 = x4[32 + mq * 3 + 0];
      const float4 a1 = x4[32 + mq * 3 + 1];
      const float4 a2 = x4[32 + mq * 3 + 2];
      const float xa[12] = {a0.x, a0.y, a0.z, a0.w, a1.x, a1.y, a1.z, a1.w,
                            a2.x, a2.y, a2.z, a2.w};
#pragma unroll
      for (int mm = 0; mm < 4; ++mm) {
        const float wv = W1u[(mq * 4 + mm) * 32];
#pragma unroll
        for (int j = 0; j < 3; ++j) h1v[j] += xa[mm * 3 + j] * wv;
      }
    }
    const float h1a = h1v[0] * H1SC, h1b = h1v[1] * H1SC, h1c = h1v[2] * H1SC;

    float h2v[5] = {0.f, 0.f, 0.f, 0.f, 0.f};
#pragma unroll 2
    for (int mq = 0; mq < 8; ++mq) {
      const float4 a0 = x4[80 + mq * 5 + 0];
      const float4 a1 = x4[80 + mq * 5 + 1];
      const float4 a2 = x4[80 + mq * 5 + 2];
      const float4 a3 = x4[80 + mq * 5 + 3];
      const float4 a4 = x4[80 + mq * 5 + 4];
      const float xa[20] = {a0.x, a0.y, a0.z, a0.w, a1.x, a1.y, a1.z, a1.w,
                            a2.x, a2.y, a2.z, a2.w, a3.x, a3.y, a3.z, a3.w,
                            a4.x, a4.y, a4.z, a4.w};
#pragma unroll
      for (int mm = 0; mm < 4; ++mm) {
        const float wv = W2u[(mq * 4 + mm) * 32];
#pragma unroll
        for (int j = 0; j < 5; ++j) h2v[j] += xa[mm * 5 + j] * wv;
      }
    }
#pragma unroll
    for (int j = 0; j < 5; ++j) h2v[j] *= H2SC;

    const float v0 = V[nloc][u],       v1 = V[nloc][u + 32],
                v2 = V[nloc][u + 64],  v3 = V[nloc][u + 96],
                v4 = V[nloc][u + 128], v5 = V[nloc][u + 160],
                v6 = V[nloc][u + 192];

    // y0: paths (0,0), (1,1)->C110, (2,2)->C220
    const float d11 = h1a * h1a + h1b * h1b + h1c * h1c;
    const float d22 = h2v[0] * h2v[0] + h2v[1] * h2v[1] + h2v[2] * h2v[2] +
                      h2v[3] * h2v[3] + h2v[4] * h2v[4];
    float y0 = v0 * h0 * h0 + v2 * d11 * ISQRT3 + v5 * d22 * ISQRT5;

    // t4 = <Q2[r], h1 h1^T>  (C112)
    const float o00 = h1a * h1a, o01 = h1a * h1b, o02 = h1a * h1c;
    const float o11 = h1b * h1b, o12 = h1b * h1c, o22 = h1c * h1c;
    const float t40 = TWOS2f * o01, t41 = TWOS2f * o12;
    const float t42 = S6f * (2.f * o22 - o00 - o11);
    const float t43 = TWOS2f * o02, t44 = S2f * (o00 - o11);

    // t8 = norm2 * <Q2[r], A^2>, A = sum_p h2[p] Q2[p]  (C222)
    const float A00 = -S6f * h2v[2] + S2f * h2v[4];
    const float A01 = S2f * h2v[0];
    const float A02 = S2f * h2v[3];
    const float A11 = -S6f * h2v[2] - S2f * h2v[4];
    const float A12 = S2f * h2v[1];
    const float A22 = TWOS6f * h2v[2];
    const float B00 = A00 * A00 + A01 * A01 + A02 * A02;
    const float B01 = A00 * A01 + A01 * A11 + A02 * A12;
    const float B02 = A00 * A02 + A01 * A12 + A02 * A22;
    const float B11 = A01 * A01 + A11 * A11 + A12 * A12;
    const float B12 = A01 * A02 + A11 * A12 + A12 * A22;
    const float B22 = A02 * A02 + A12 * A12 + A22 * A22;
    const float t80 = TWOS2f * B01, t81 = TWOS2f * B12;
    const float t82 = S6f * (2.f * B22 - B00 - B11);
    const float t83 = TWOS2f * B02, t84 = S2f * (B00 - B11);

    const float w15 = (v1 + v4) * h0;  // C022 + C202 share t[r] = h0*h2[r]
    const float v6n = v6 * norm2;
    float y2r[5];
    y2r[0] = w15 * h2v[0] + v3 * t40 + v6n * t80;
    y2r[1] = w15 * h2v[1] + v3 * t41 + v6n * t81;
    y2r[2] = w15 * h2v[2] + v3 * t42 + v6n * t82;
    y2r[3] = w15 * h2v[3] + v3 * t43 + v6n * t83;
    y2r[4] = w15 * h2v[4] + v3 * t44 + v6n * t84;

#pragma unroll
    for (int off = 16; off > 0; off >>= 1) {
      y0 += __shfl_xor(y0, off, 32);
#pragma unroll
      for (int r = 0; r < 5; ++r) y2r[r] += __shfl_xor(y2r[r], off, 32);
    }
    if (u == 0) {
      sphs[nloc][0] = y0;
#pragma unroll
      for (int r = 0; r < 5; ++r) sphs[nloc][1 + r] = y2r[r];
    }
  }
  __syncthreads();

  // ---- phase 4: cart + segment-merged atomics ----
  if (tid < 9) {
    const float QW[9][6] = {
        {ISQRT3, 0.f, 0.f, -S6f, 0.f, S2f},
        {0.f, S2f, 0.f, 0.f, 0.f, 0.f},
        {0.f, 0.f, 0.f, 0.f, S2f, 0.f},
        {0.f, S2f, 0.f, 0.f, 0.f, 0.f},
        {ISQRT3, 0.f, 0.f, -S6f, 0.f, -S2f},
        {0.f, 0.f, S2f, 0.f, 0.f, 0.f},
        {0.f, 0.f, 0.f, 0.f, S2f, 0.f},
        {0.f, 0.f, S2f, 0.f, 0.f, 0.f},
        {ISQRT3, 0.f, 0.f, TWOS6f, 0.f, 0.f}};
    const int a = tid / 3, b = tid % 3;
    const int rolled = ((a + 1) % 3) * 3 + ((b + 1) % 3);
    const float c0 = QW[tid][0], c1 = QW[tid][1], c2 = QW[tid][2];
    const float c3 = QW[tid][3], c4 = QW[tid][4], c5 = QW[tid][5];
    int cur_g = batch_s[0];
    float acc = 0.f;
#pragma unroll 4
    for (int q = 0; q < 32; ++q) {
      const int g = batch_s[q];
      const float val = c0 * sphs[q][0] + c1 * sphs[q][1] + c2 * sphs[q][2] +
                        c3 * sphs[q][3] + c4 * sphs[q][4] + c5 * sphs[q][5];
      if (g != cur_g) {
        atomicAdd(out + cur_g * 9 + rolled, acc);
        acc = 0.f;
        cur_g = g;
      }
      acc += val;
    }
    atomicAdd(out + cur_g * 9 + rolled, acc);
  }
}

extern "C" void kernel_launch(void* const* d_in, const int* in_sizes, int n_in,
                              void* d_out, int out_size, void* d_ws, size_t ws_size,
                              hipStream_t stream) {
  const float* x_scalar = (const float*)d_in[0];
  const float* x_sph    = (const float*)d_in[1];
  const int*   batch    = (const int*)d_in[2];
  const float* W0e      = (const float*)d_in[3];
  const float* W1o      = (const float*)d_in[4];
  const float* W2e      = (const float*)d_in[5];
  const float* Wm1      = (const float*)d_in[6];
  const float* bm1      = (const float*)d_in[7];
  const float* Wm2      = (const float*)d_in[8];
  const float* bm2      = (const float*)d_in[9];
  const float* P0       = (const float*)d_in[10];
  // P1 (d_in[11]) is provably unused: C111/C221 are antisymmetric, contracted with h(x)h of the same h.
  const float* P2       = (const float*)d_in[12];
  float* ws  = (float*)d_ws;
  float* out = (float*)d_out;

  if (ws_size < (size_t)WS_FLOATS * sizeof(float)) return;

  // ---- host-side C222 normalization (pure CPU double math, no HIP calls) ----
  double Q2[5][3][3] = {};
  const double s2d = 0.70710678118654752440, s6d = 0.40824829046386301637;
  Q2[0][0][1] = Q2[0][1][0] = s2d;
  Q2[1][1][2] = Q2[1][2][1] = s2d;
  Q2[2][0][0] = Q2[2][1][1] = -s6d; Q2[2][2][2] = 2.0 * s6d;
  Q2[3][0][2] = Q2[3][2][0] = s2d;
  Q2[4][0][0] = s2d; Q2[4][1][1] = -s2d;
  double eps[3][3][3] = {};
  eps[0][1][2] = eps[1][2][0] = eps[2][0][1] = 1.0;
  eps[0][2][1] = eps[2][1][0] = eps[1][0][2] = -1.0;
  (void)eps;
  double ss = 0.0;
  for (int i = 0; i < 5; ++i)
    for (int jj = 0; jj < 5; ++jj) {
      double S[3][3];
      for (int a = 0; a < 3; ++a)
        for (int d = 0; d < 3; ++d) {
          double m1 = 0, m2 = 0;
          for (int b = 0; b < 3; ++b) {
            m1 += Q2[i][a][b] * Q2[jj][d][b];
            m2 += Q2[i][d][b] * Q2[jj][a][b];
          }
          S[a][d] = 0.5 * (m1 + m2);
        }
      double tr = (S[0][0] + S[1][1] + S[2][2]) / 3.0;
      S[0][0] -= tr; S[1][1] -= tr; S[2][2] -= tr;
      for (int kk = 0; kk < 5; ++kk) {
        double cc = 0;
        for (int a = 0; a < 3; ++a)
          for (int d = 0; d < 3; ++d) cc += Q2[kk][a][d] * S[a][d];
        ss += cc * cc;
      }
    }
  const float norm2 = (float)sqrt(5.0 / ss);   // = sqrt(12/7)

  prep_kernel<<<57, 256, 0, stream>>>(Wm2, bm2, P0, P2, ws, out);
  fused_kernel<<<625, 256, 0, stream>>>(x_scalar, x_sph, batch, W0e, W1o, W2e,
                                        Wm1, bm1, ws, out, norm2);
}

// Round 3
// 158.607 us; speedup vs baseline: 1.2607x; 1.2607x over previous
//
#include <hip/hip_runtime.h>
#include <math.h>

// ---------------- workspace layout (float offsets) ----------------
#define OFF_W2P 0              // [64][224]  Wm2 pre-contracted with P
#define OFF_B2P 14336          // [224]
#define OFF_V   14592          // [20000][224]
#define OFF_H0  4494592        // [20000][32]
#define OFF_H1  5134592        // [20000][3][32]
#define OFF_H2  7054592        // [20000][5][32]
#define WS_FLOATS 10254592

#define SC_Y0 0.0180421959121758f   // (1/sqrt(32))*(1/sqrt(96))
#define SC_Y2 0.015625f             // (1/sqrt(32))*(1/sqrt(128))
#define S2f 0.70710678118654752f
#define S6f 0.40824829046386302f
#define TWOS2f 1.41421356237309505f
#define TWOS6f 0.81649658092772603f
#define ISQRT3 0.57735026918962576f
#define ISQRT5 0.44721359549995794f
#define H0SC 0.08838834764831845f   // 1/sqrt(128)
#define H1SC 0.125f                 // 1/sqrt(64)
#define H2SC 0.17677669529663689f   // 1/sqrt(32)

__device__ __constant__ int KARR[7] = {0, 1, 2, 4, 5, 6, 8};

// ---------------- prep: Wm2p, bm2p, zero out ----------------
__global__ __launch_bounds__(256) void prep_kernel(
    const float* __restrict__ Wm2, const float* __restrict__ bm2,
    const float* __restrict__ P0, const float* __restrict__ P2,
    float* __restrict__ ws, float* __restrict__ out) {
  int j = blockIdx.x * 256 + threadIdx.x;
  if (j < 2304) out[j] = 0.f;

  if (j < 14336) {
    int s = j >> 11; int rem = j & 2047; int c = rem >> 5; int u = rem & 31;
    int k = KARR[s];
    const float* P;
    float sc;
    switch (s) {
      case 0: P = P0;      sc = SC_Y0; break;
      case 1: P = P2;      sc = SC_Y2; break;
      case 2: P = P0 + 32; sc = SC_Y0; break;
      case 3: P = P2 + 32; sc = SC_Y2; break;
      case 4: P = P2 + 64; sc = SC_Y2; break;
      case 5: P = P0 + 64; sc = SC_Y0; break;
      default: P = P2 + 96; sc = SC_Y2; break;
    }
    const float4* w4 = (const float4*)(Wm2 + c * 9216 + k * 1024 + u * 32);
    const float4* p4 = (const float4*)P;
    float acc = 0.f;
#pragma unroll
    for (int q = 0; q < 8; ++q) {
      float4 a = w4[q], b = p4[q];
      acc += a.x * b.x + a.y * b.y + a.z * b.z + a.w * b.w;
    }
    ws[OFF_W2P + c * 224 + s * 32 + u] = acc * sc;
  } else if (j < 14560) {
    int i = j - 14336; int s = i >> 5; int u = i & 31; int k = KARR[s];
    const float* P;
    float sc;
    switch (s) {
      case 0: P = P0;      sc = SC_Y0; break;
      case 1: P = P2;      sc = SC_Y2; break;
      case 2: P = P0 + 32; sc = SC_Y0; break;
      case 3: P = P2 + 32; sc = SC_Y2; break;
      case 4: P = P2 + 64; sc = SC_Y2; break;
      case 5: P = P0 + 64; sc = SC_Y0; break;
      default: P = P2 + 96; sc = SC_Y2; break;
    }
    const float* b = bm2 + k * 1024 + u * 32;
    float acc = 0.f;
#pragma unroll
    for (int w = 0; w < 32; ++w) acc += b[w] * P[w];
    ws[OFF_B2P + s * 32 + u] = acc * sc;
  }
}

// ---------------- kbc: blocks [0,625) = KB (hidden+V), [625,1875) = KC (h) ----------------
// KB LDS: xs[32][132] @0 (16896 B), hiT[64][36] @16896 (9216 B)  -> 26112 B
// KC LDS: xp[16][484] @0                                         -> 30976 B
__global__ __launch_bounds__(256, 1) void kbc_kernel(
    const float* __restrict__ xs_g, const float* __restrict__ xsph,
    const float* __restrict__ W0e, const float* __restrict__ W1o,
    const float* __restrict__ W2e,
    const float* __restrict__ Wm1, const float* __restrict__ bm1,
    float* __restrict__ ws) {
  __shared__ __align__(16) char smem[30976];
  const int tid = threadIdx.x;

  if (blockIdx.x < 625) {
    // ================= KB: hidden = silu(x@Wm1+b); V = hidden@W2p + b2p =================
    float (*xs)[132] = (float (*)[132])smem;
    float (*hiT)[36] = (float (*)[36])(smem + 16896);
    const int n0 = blockIdx.x * 32;

    for (int idx = tid; idx < 1024; idx += 256) {
      const int row = idx >> 5, c4 = idx & 31;
      *(float4*)&xs[row][c4 * 4] = *(const float4*)(xs_g + (n0 + row) * 128 + c4 * 4);
    }
    __syncthreads();

    {  // hidden: 2n x 4c per thread
      const int cg = tid & 15, ng = tid >> 4;
      const int c0 = cg * 4, nl = ng * 2;
      float acc[2][4] = {{0.f}};
#pragma unroll 4
      for (int mq = 0; mq < 32; ++mq) {
        float4 xv[2];
        xv[0] = *(float4*)&xs[nl][mq * 4];
        xv[1] = *(float4*)&xs[nl + 1][mq * 4];
        float4 wv[4];
#pragma unroll
        for (int r = 0; r < 4; ++r) wv[r] = *(const float4*)(Wm1 + (mq * 4 + r) * 64 + c0);
#pragma unroll
        for (int r = 0; r < 4; ++r) {
          const float4 w = wv[r];
#pragma unroll
          for (int i = 0; i < 2; ++i) {
            const float xr = (r == 0) ? xv[i].x : (r == 1) ? xv[i].y : (r == 2) ? xv[i].z : xv[i].w;
            acc[i][0] += xr * w.x; acc[i][1] += xr * w.y;
            acc[i][2] += xr * w.z; acc[i][3] += xr * w.w;
          }
        }
      }
      const float4 bb = *(const float4*)(bm1 + c0);
#pragma unroll
      for (int jj = 0; jj < 4; ++jj) {
        float zz[2];
#pragma unroll
        for (int i = 0; i < 2; ++i) {
          float z = acc[i][jj] + ((jj == 0) ? bb.x : (jj == 1) ? bb.y : (jj == 2) ? bb.z : bb.w);
          zz[i] = z / (1.f + __expf(-z));
        }
        *(float2*)&hiT[c0 + jj][nl] = make_float2(zz[0], zz[1]);
      }
    }
    __syncthreads();

    if (tid < 224) {  // V: 4n x 8o per thread -> global ws
      const int og = tid >> 3, ng = tid & 7;
      const int o0 = og * 8, nl = ng * 4;
      const float4 blo = *(const float4*)(ws + OFF_B2P + o0);
      const float4 bhi = *(const float4*)(ws + OFF_B2P + o0 + 4);
      float acc[4][8];
#pragma unroll
      for (int i = 0; i < 4; ++i) {
        acc[i][0] = blo.x; acc[i][1] = blo.y; acc[i][2] = blo.z; acc[i][3] = blo.w;
        acc[i][4] = bhi.x; acc[i][5] = bhi.y; acc[i][6] = bhi.z; acc[i][7] = bhi.w;
      }
#pragma unroll 2
      for (int c = 0; c < 64; ++c) {
        const float4 hv = *(float4*)&hiT[c][nl];
        const float4 wlo = *(const float4*)(ws + OFF_W2P + c * 224 + o0);
        const float4 whi = *(const float4*)(ws + OFF_W2P + c * 224 + o0 + 4);
        const float hvv[4] = {hv.x, hv.y, hv.z, hv.w};
        const float wv[8] = {wlo.x, wlo.y, wlo.z, wlo.w, whi.x, whi.y, whi.z, whi.w};
#pragma unroll
        for (int i = 0; i < 4; ++i)
#pragma unroll
          for (int jj = 0; jj < 8; ++jj) acc[i][jj] += hvv[i] * wv[jj];
      }
#pragma unroll
      for (int i = 0; i < 4; ++i) {
        const int n = n0 + nl + i;
        float4 a = {acc[i][0], acc[i][1], acc[i][2], acc[i][3]};
        float4 b = {acc[i][4], acc[i][5], acc[i][6], acc[i][7]};
        *(float4*)(ws + OFF_V + n * 224 + o0) = a;
        *(float4*)(ws + OFF_V + n * 224 + o0 + 4) = b;
      }
    }
  } else {
    // ================= KC: h0/h1/h2 projections, 16-node tile =================
    float (*xp)[484] = (float (*)[484])smem;
    const int n0 = (blockIdx.x - 625) * 16;

    for (int idx = tid; idx < 1920; idx += 256) {
      const int row = idx / 120, c4 = idx % 120;
      *(float4*)&xp[row][c4 * 4] = *(const float4*)(xsph + (size_t)(n0 + row) * 480 + c4 * 4);
    }
    __syncthreads();

    if (tid < 64) {  // h0 (K=128): 1n x 8u
      const int n = tid & 15, ug = tid >> 4;
      const int u0 = ug * 8;
      float acc[8] = {0.f};
#pragma unroll 4
      for (int mq = 0; mq < 32; ++mq) {
        const float4 xv = *(float4*)&xp[n][mq * 4];
        const float xa[4] = {xv.x, xv.y, xv.z, xv.w};
#pragma unroll
        for (int r = 0; r < 4; ++r) {
          const float4 wl = *(const float4*)(W0e + (mq * 4 + r) * 32 + u0);
          const float4 wh = *(const float4*)(W0e + (mq * 4 + r) * 32 + u0 + 4);
          const float xr = xa[r];
          acc[0] += xr * wl.x; acc[1] += xr * wl.y; acc[2] += xr * wl.z; acc[3] += xr * wl.w;
          acc[4] += xr * wh.x; acc[5] += xr * wh.y; acc[6] += xr * wh.z; acc[7] += xr * wh.w;
        }
      }
      const int n_g = n0 + n;
      float4 a = {acc[0] * H0SC, acc[1] * H0SC, acc[2] * H0SC, acc[3] * H0SC};
      float4 b = {acc[4] * H0SC, acc[5] * H0SC, acc[6] * H0SC, acc[7] * H0SC};
      *(float4*)(ws + OFF_H0 + n_g * 32 + u0) = a;
      *(float4*)(ws + OFF_H0 + n_g * 32 + u0 + 4) = b;
    } else if (tid < 128) {  // h1 (K=64, 3 comps): 1n x 8u x 3j
      const int t = tid - 64;
      const int n = t & 15, ug = t >> 4;
      const int u0 = ug * 8;
      float acc[3][8] = {{0.f}};
#pragma unroll 2
      for (int mq = 0; mq < 16; ++mq) {
        const float4 a0 = *(float4*)&xp[n][128 + mq * 12];
        const float4 a1 = *(float4*)&xp[n][128 + mq * 12 + 4];
        const float4 a2 = *(float4*)&xp[n][128 + mq * 12 + 8];
        const float xa[12] = {a0.x, a0.y, a0.z, a0.w, a1.x, a1.y, a1.z, a1.w,
                              a2.x, a2.y, a2.z, a2.w};
#pragma unroll
        for (int mm = 0; mm < 4; ++mm) {
          const float4 wl = *(const float4*)(W1o + (mq * 4 + mm) * 32 + u0);
          const float4 wh = *(const float4*)(W1o + (mq * 4 + mm) * 32 + u0 + 4);
          const float wv[8] = {wl.x, wl.y, wl.z, wl.w, wh.x, wh.y, wh.z, wh.w};
#pragma unroll
          for (int j = 0; j < 3; ++j) {
            const float xr = xa[mm * 3 + j];
#pragma unroll
            for (int jj = 0; jj < 8; ++jj) acc[j][jj] += xr * wv[jj];
          }
        }
      }
      const int n_g = n0 + n;
#pragma unroll
      for (int j = 0; j < 3; ++j) {
        float4 a = {acc[j][0] * H1SC, acc[j][1] * H1SC, acc[j][2] * H1SC, acc[j][3] * H1SC};
        float4 b = {acc[j][4] * H1SC, acc[j][5] * H1SC, acc[j][6] * H1SC, acc[j][7] * H1SC};
        *(float4*)(ws + OFF_H1 + (n_g * 3 + j) * 32 + u0) = a;
        *(float4*)(ws + OFF_H1 + (n_g * 3 + j) * 32 + u0 + 4) = b;
      }
    } else if (tid < 192) {  // h2 (K=32, 5 comps): 1n x 8u x 5j
      const int t = tid - 128;
      const int n = t & 15, ug = t >> 4;
      const int u0 = ug * 8;
      float acc[5][8] = {{0.f}};
#pragma unroll 2
      for (int mq = 0; mq < 8; ++mq) {
        const float4 a0 = *(float4*)&xp[n][320 + mq * 20];
        const float4 a1 = *(float4*)&xp[n][320 + mq * 20 + 4];
        const float4 a2 = *(float4*)&xp[n][320 + mq * 20 + 8];
        const float4 a3 = *(float4*)&xp[n][320 + mq * 20 + 12];
        const float4 a4 = *(float4*)&xp[n][320 + mq * 20 + 16];
        const float xa[20] = {a0.x, a0.y, a0.z, a0.w, a1.x, a1.y, a1.z, a1.w,
                              a2.x, a2.y, a2.z, a2.w, a3.x, a3.y, a3.z, a3.w,
                              a4.x, a4.y, a4.z, a4.w};
#pragma unroll
        for (int mm = 0; mm < 4; ++mm) {
          const float4 wl = *(const float4*)(W2e + (mq * 4 + mm) * 32 + u0);
          const float4 wh = *(const float4*)(W2e + (mq * 4 + mm) * 32 + u0 + 4);
          const float wv[8] = {wl.x, wl.y, wl.z, wl.w, wh.x, wh.y, wh.z, wh.w};
#pragma unroll
          for (int j = 0; j < 5; ++j) {
            const float xr = xa[mm * 5 + j];
#pragma unroll
            for (int jj = 0; jj < 8; ++jj) acc[j][jj] += xr * wv[jj];
          }
        }
      }
      const int n_g = n0 + n;
#pragma unroll
      for (int j = 0; j < 5; ++j) {
        float4 a = {acc[j][0] * H2SC, acc[j][1] * H2SC, acc[j][2] * H2SC, acc[j][3] * H2SC};
        float4 b = {acc[j][4] * H2SC, acc[j][5] * H2SC, acc[j][6] * H2SC, acc[j][7] * H2SC};
        *(float4*)(ws + OFF_H2 + (n_g * 5 + j) * 32 + u0) = a;
        *(float4*)(ws + OFF_H2 + (n_g * 5 + j) * 32 + u0 + 4) = b;
      }
    }
  }
}

// ---------------- KD: path math + reduce + segment atomics ----------------
__global__ __launch_bounds__(256) void kd_kernel(
    const float* __restrict__ ws, const int* __restrict__ batch,
    float* __restrict__ out, const float norm2) {
  const int tid = threadIdx.x;
  const int nl = tid >> 5, un = tid & 31;
  const int n0 = blockIdx.x * 8;
  const int n = n0 + nl;

  const float* V = ws + OFF_V + n * 224 + un;
  const float v0 = V[0], v1 = V[32], v2 = V[64], v3 = V[96];
  const float v4 = V[128], v5 = V[160], v6 = V[192];
  const float h0 = ws[OFF_H0 + n * 32 + un];
  const float h1a = ws[OFF_H1 + (n * 3 + 0) * 32 + un];
  const float h1b = ws[OFF_H1 + (n * 3 + 1) * 32 + un];
  const float h1c = ws[OFF_H1 + (n * 3 + 2) * 32 + un];
  float h2v[5];
#pragma unroll
  for (int j = 0; j < 5; ++j) h2v[j] = ws[OFF_H2 + (n * 5 + j) * 32 + un];

  const float d11 = h1a * h1a + h1b * h1b + h1c * h1c;
  const float d22 = h2v[0] * h2v[0] + h2v[1] * h2v[1] + h2v[2] * h2v[2] +
                    h2v[3] * h2v[3] + h2v[4] * h2v[4];
  float y0 = v0 * h0 * h0 + v2 * d11 * ISQRT3 + v5 * d22 * ISQRT5;

  const float o00 = h1a * h1a, o01 = h1a * h1b, o02 = h1a * h1c;
  const float o11 = h1b * h1b, o12 = h1b * h1c, o22 = h1c * h1c;
  const float t40 = TWOS2f * o01, t41 = TWOS2f * o12;
  const float t42 = S6f * (2.f * o22 - o00 - o11);
  const float t43 = TWOS2f * o02, t44 = S2f * (o00 - o11);

  const float A00 = -S6f * h2v[2] + S2f * h2v[4];
  const float A01 = S2f * h2v[0];
  const float A02 = S2f * h2v[3];
  const float A11 = -S6f * h2v[2] - S2f * h2v[4];
  const float A12 = S2f * h2v[1];
  const float A22 = TWOS6f * h2v[2];
  const float B00 = A00 * A00 + A01 * A01 + A02 * A02;
  const float B01 = A00 * A01 + A01 * A11 + A02 * A12;
  const float B02 = A00 * A02 + A01 * A12 + A02 * A22;
  const float B11 = A01 * A01 + A11 * A11 + A12 * A12;
  const float B12 = A01 * A02 + A11 * A12 + A12 * A22;
  const float B22 = A02 * A02 + A12 * A12 + A22 * A22;
  const float t80 = TWOS2f * B01, t81 = TWOS2f * B12;
  const float t82 = S6f * (2.f * B22 - B00 - B11);
  const float t83 = TWOS2f * B02, t84 = S2f * (B00 - B11);

  const float w15 = (v1 + v4) * h0;
  const float v6n = v6 * norm2;
  float y2r[5];
  y2r[0] = w15 * h2v[0] + v3 * t40 + v6n * t80;
  y2r[1] = w15 * h2v[1] + v3 * t41 + v6n * t81;
  y2r[2] = w15 * h2v[2] + v3 * t42 + v6n * t82;
  y2r[3] = w15 * h2v[3] + v3 * t43 + v6n * t83;
  y2r[4] = w15 * h2v[4] + v3 * t44 + v6n * t84;

#pragma unroll
  for (int off = 16; off > 0; off >>= 1) {
    y0 += __shfl_xor(y0, off, 32);
#pragma unroll
    for (int r = 0; r < 5; ++r) y2r[r] += __shfl_xor(y2r[r], off, 32);
  }

  __shared__ float sphs[8][6];
  if (un == 0) {
    sphs[nl][0] = y0;
#pragma unroll
    for (int r = 0; r < 5; ++r) sphs[nl][1 + r] = y2r[r];
  }
  __syncthreads();

  if (tid < 9) {
    const float QW[9][6] = {
        {ISQRT3, 0.f, 0.f, -S6f, 0.f, S2f},
        {0.f, S2f, 0.f, 0.f, 0.f, 0.f},
        {0.f, 0.f, 0.f, 0.f, S2f, 0.f},
        {0.f, S2f, 0.f, 0.f, 0.f, 0.f},
        {ISQRT3, 0.f, 0.f, -S6f, 0.f, -S2f},
        {0.f, 0.f, S2f, 0.f, 0.f, 0.f},
        {0.f, 0.f, 0.f, 0.f, S2f, 0.f},
        {0.f, 0.f, S2f, 0.f, 0.f, 0.f},
        {ISQRT3, 0.f, 0.f, TWOS6f, 0.f, 0.f}};
    const int a = tid / 3, b = tid % 3;
    const int rolled = ((a + 1) % 3) * 3 + ((b + 1) % 3);
    const float c0 = QW[tid][0], c1 = QW[tid][1], c2 = QW[tid][2];
    const float c3 = QW[tid][3], c4 = QW[tid][4], c5 = QW[tid][5];
    int cur_g = batch[n0];
    float acc = 0.f;
#pragma unroll
    for (int q = 0; q < 8; ++q) {
      const int g = batch[n0 + q];
      const float val = c0 * sphs[q][0] + c1 * sphs[q][1] + c2 * sphs[q][2] +
                        c3 * sphs[q][3] + c4 * sphs[q][4] + c5 * sphs[q][5];
      if (g != cur_g) {
        atomicAdd(out + cur_g * 9 + rolled, acc);
        acc = 0.f;
        cur_g = g;
      }
      acc += val;
    }
    atomicAdd(out + cur_g * 9 + rolled, acc);
  }
}

extern "C" void kernel_launch(void* const* d_in, const int* in_sizes, int n_in,
                              void* d_out, int out_size, void* d_ws, size_t ws_size,
                              hipStream_t stream) {
  const float* x_scalar = (const float*)d_in[0];
  const float* x_sph    = (const float*)d_in[1];
  const int*   batch    = (const int*)d_in[2];
  const float* W0e      = (const float*)d_in[3];
  const float* W1o      = (const float*)d_in[4];
  const float* W2e      = (const float*)d_in[5];
  const float* Wm1      = (const float*)d_in[6];
  const float* bm1      = (const float*)d_in[7];
  const float* Wm2      = (const float*)d_in[8];
  const float* bm2      = (const float*)d_in[9];
  const float* P0       = (const float*)d_in[10];
  // P1 (d_in[11]) provably unused: C111/C221 antisymmetric vs h(x)h of same h.
  const float* P2       = (const float*)d_in[12];
  float* ws  = (float*)d_ws;
  float* out = (float*)d_out;

  if (ws_size < (size_t)WS_FLOATS * sizeof(float)) return;

  // host-side C222 normalization (pure CPU double math; = sqrt(12/7))
  double Q2[5][3][3] = {};
  const double s2d = 0.70710678118654752440, s6d = 0.40824829046386301637;
  Q2[0][0][1] = Q2[0][1][0] = s2d;
  Q2[1][1][2] = Q2[1][2][1] = s2d;
  Q2[2][0][0] = Q2[2][1][1] = -s6d; Q2[2][2][2] = 2.0 * s6d;
  Q2[3][0][2] = Q2[3][2][0] = s2d;
  Q2[4][0][0] = s2d; Q2[4][1][1] = -s2d;
  double ss = 0.0;
  for (int i = 0; i < 5; ++i)
    for (int jj = 0; jj < 5; ++jj) {
      double S[3][3];
      for (int a = 0; a < 3; ++a)
        for (int d = 0; d < 3; ++d) {
          double m1 = 0, m2 = 0;
          for (int b = 0; b < 3; ++b) {
            m1 += Q2[i][a][b] * Q2[jj][d][b];
            m2 += Q2[i][d][b] * Q2[jj][a][b];
          }
          S[a][d] = 0.5 * (m1 + m2);
        }
      double tr = (S[0][0] + S[1][1] + S[2][2]) / 3.0;
      S[0][0] -= tr; S[1][1] -= tr; S[2][2] -= tr;
      for (int kk = 0; kk < 5; ++kk) {
        double cc = 0;
        for (int a = 0; a < 3; ++a)
          for (int d = 0; d < 3; ++d) cc += Q2[kk][a][d] * S[a][d];
        ss += cc * cc;
      }
    }
  const float norm2 = (float)sqrt(5.0 / ss);

  prep_kernel<<<57, 256, 0, stream>>>(Wm2, bm2, P0, P2, ws, out);
  kbc_kernel<<<1875, 256, 0, stream>>>(x_scalar, x_sph, W0e, W1o, W2e, Wm1, bm1, ws);
  kd_kernel<<<2500, 256, 0, stream>>>(ws, batch, out, norm2);
}